// Round 3
// baseline (425.328 us; speedup 1.0000x reference)
//
#include <hip/hip_runtime.h>
#include <stdint.h>

#define B_   16
#define C_   512
#define H_   64
#define W_   64
#define NH_  8
#define HD_  64
#define HW_  4096

typedef __attribute__((ext_vector_type(8))) _Float16 f16x8;
typedef __attribute__((ext_vector_type(8))) unsigned short u16x8;
typedef __attribute__((ext_vector_type(4))) unsigned short u16x4;
typedef __attribute__((ext_vector_type(4))) float f32x4;

static __device__ __forceinline__ unsigned short f2h(float f) {
  _Float16 h = (_Float16)f;
  unsigned short u;
  __builtin_memcpy(&u, &h, 2);
  return u;
}

static __device__ __forceinline__ void gld_lds16(const void* g, void* l) {
  __builtin_amdgcn_global_load_lds((__attribute__((address_space(1))) void*)g,
                                   (__attribute__((address_space(3))) void*)l,
                                   16, 0, 0);
}

// ---------------- K0b: wq|wk|wv (512,512) fp32 -> Wc (1536,512) f16
__global__ __launch_bounds__(256) void rcca_cvtw(const float* __restrict__ wq,
                                                 const float* __restrict__ wk,
                                                 const float* __restrict__ wv,
                                                 unsigned short* __restrict__ Wc) {
  const int i = blockIdx.x * 256 + threadIdx.x;  // 196608 threads
  const int e = i * 4;
  const float* w = (e < 262144) ? wq : (e < 524288) ? wk : wv;
  const int off = e & 262143;
  const float4 v = *(const float4*)(w + off);
  u16x4 p;
  p[0] = f2h(v.x); p[1] = f2h(v.y); p[2] = f2h(v.z); p[3] = f2h(v.w);
  *(u16x4*)(Wc + e) = p;
}

// ---------------- K1: fused QKV projection + attention + residual, with in-LDS transpose.
// Block = (b, head, ht): GEMM M=128 (2 h-rows x 64 w), N=192 (q|k|v of one head), K=512.
// Per K-step: gld_lds x-tile [64 c][128 hw] fp32 -> scratch (coalesced, rows of 512B),
// transpose+convert in LDS -> lA [128 hw][64 c] f16 (XOR chunk-swizzled), B via gld_lds f16.
// Epilogue writes Q/K/V (+bias) to LDS, then per-row attention, then out = O + x.
// XCD swizzle: 8 consecutive logical blocks (the 8 heads sharing one A-tile) on one XCD.
__global__ __launch_bounds__(256) void rcca_fused(
    const float* __restrict__ x, const unsigned short* __restrict__ Wc,
    const float* __restrict__ bq, const float* __restrict__ bk, const float* __restrict__ bv,
    float* __restrict__ out) {
  __shared__ __align__(16) char smem[73728];
  // K-loop:  [0,16384)     lA [128][64] f16 swizzled
  //          [16384,40960) lB [192][64] f16 swizzled
  //          [40960,73728) sX [64 c][128 hw] fp32 scratch (dead after K-loop)
  // attn:    [hs*27648+0)      sQ[hs] [64][72] f16
  //          [hs*27648+9216)   sK[hs] [64][72] f16
  //          [hs*27648+18432)  sV[hs] [64][72] f16 (d-major)
  //          [55296+hs*9216)   sP[hs] [64][72] f16
  //          sO[hs] f32 [64][66] overlays sQ[hs]+sK[hs]
  unsigned short* lA = (unsigned short*)smem;
  unsigned short* lB = (unsigned short*)(smem + 16384);
  float* sX = (float*)(smem + 40960);
  const int sbid = blockIdx.x;
  const int lg = ((sbid & 7) << 9) | (sbid >> 3);  // bijective: 4096 % 8 == 0
  const int head = lg & 7;
  const int bh = lg >> 3;
  const int b = bh >> 5;
  const int ht = bh & 31;
  const int t = threadIdx.x;
  const int wid = t >> 6, lane = t & 63, r = lane & 15, q = lane >> 4;
  const int rx = r & 7;
  const int wm = wid >> 1, wn = wid & 1;  // wm = h-row (hs), wn = n-half (GEMM) / q-row-half (attn)
  const int arow = t >> 3;
  const int acol = ((t & 7) ^ (arow & 7)) * 8;  // swizzled ushort col (B staging)
  char* lBb = (char*)lB;
  char* sXb = (char*)sX;
  const int wbase = wid * 1024;
  // A scratch source: idx = rr*256 + t; c = idx>>5; hw-chunk = idx&31 (16B = 4 floats)
  const int xc = t >> 5;          // c within pair-of-rows group (relative, 0..7 via rr)
  const int xch = t & 31;         // 16B chunk within c-row
  const float* Xbase = x + (size_t)b * C_ * HW_ + (size_t)ht * 128;
  const unsigned short* Bbase = Wc + (size_t)head * 64 * C_;
  // transpose pass mapping: thread -> (hw row, c-half)
  const int thw = t >> 1, thalf = t & 1;
  f32x4 acc[4][6];
#pragma unroll
  for (int i = 0; i < 4; ++i)
#pragma unroll
    for (int j = 0; j < 6; ++j) acc[i][j] = (f32x4){0.f, 0.f, 0.f, 0.f};

  for (int k0 = 0; k0 < C_; k0 += 64) {
    __syncthreads();
    // stage x-tile (fp32, [64 c][128 hw]) into sX, linear: 8 x 16B per thread
#pragma unroll
    for (int rr = 0; rr < 8; ++rr) {
      const int c = rr * 8 + xc;
      gld_lds16(Xbase + (size_t)(k0 + c) * HW_ + xch * 4, sXb + rr * 4096 + wbase);
    }
    // stage B-panel (f16) into lB, swizzled via pre-swizzled global col
#pragma unroll
    for (int p = 0; p < 6; ++p) {
      const size_t grow = (size_t)((p >> 1) * 512 + (p & 1) * 32 + arow) * C_;
      gld_lds16(Bbase + grow + k0 + acol, lBb + p * 4096 + wbase);
    }
    __syncthreads();
    // transpose+convert: sX[c][hw] fp32 -> lA[hw][c] f16 (chunk-swizzled)
#pragma unroll
    for (int u = 0; u < 4; ++u) {
      const int chunk = thalf * 4 + u;
      u16x8 pk;
#pragma unroll
      for (int j = 0; j < 8; ++j)
        pk[j] = f2h(sX[(chunk * 8 + j) * 128 + thw]);
      *(u16x8*)&lA[thw * 64 + ((chunk ^ (thw & 7)) * 8)] = pk;
    }
    __syncthreads();
#pragma unroll
    for (int kk = 0; kk < 64; kk += 32) {
      const int cb = ((kk >> 3) + q) ^ rx;
      f16x8 av[4], bw[6];
#pragma unroll
      for (int i = 0; i < 4; ++i)
        av[i] = *(const f16x8*)&lA[(wm * 64 + i * 16 + r) * 64 + cb * 8];
#pragma unroll
      for (int j = 0; j < 6; ++j)
        bw[j] = *(const f16x8*)&lB[(wn * 96 + j * 16 + r) * 64 + cb * 8];
#pragma unroll
      for (int i = 0; i < 4; ++i)
#pragma unroll
        for (int j = 0; j < 6; ++j)
          acc[i][j] = __builtin_amdgcn_mfma_f32_16x16x32_f16(av[i], bw[j], acc[i][j], 0, 0, 0);
    }
  }
  __syncthreads();
  // ---- epilogue: acc -> sQ/sK/sV of row hs=wm, bias fused.
  // C layout: m = wm*64 + i*16 + q*4 + reg (w = m&63); n = wn*96 + j*16 + r.
  unsigned short* sQh = (unsigned short*)(smem + wm * 27648);
  unsigned short* sKh = (unsigned short*)(smem + wm * 27648 + 9216);
  unsigned short* sVh = (unsigned short*)(smem + wm * 27648 + 18432);
#pragma unroll
  for (int j = 0; j < 6; ++j) {
    const int n0 = wn * 96 + j * 16;
    const int sel = n0 >> 6;          // 0=q 1=k 2=v (16-aligned frags never straddle)
    const int dd = (n0 & 63) + r;
    const float* bias = (sel == 0) ? bq : (sel == 1) ? bk : bv;
    const float bias_v = bias[head * 64 + dd];
    if (sel < 2) {
      unsigned short* dst = (sel == 0) ? sQh : sKh;
#pragma unroll
      for (int i = 0; i < 4; ++i)
#pragma unroll
        for (int reg = 0; reg < 4; ++reg)
          dst[(i * 16 + q * 4 + reg) * 72 + dd] = f2h(acc[i][j][reg] + bias_v);
    } else {
#pragma unroll
      for (int i = 0; i < 4; ++i) {
        u16x4 pk;
#pragma unroll
        for (int reg = 0; reg < 4; ++reg) pk[reg] = f2h(acc[i][j][reg] + bias_v);
        *(u16x4*)&sVh[dd * 72 + i * 16 + q * 4] = pk;  // sV is [d][w]
      }
    }
  }
  __syncthreads();
  // ---- attention: wave (wm=hs, wn=q-row half). S = Q K^T, softmax, O = P V.
  unsigned short* sPh = (unsigned short*)(smem + 55296 + wm * 9216);
  f32x4 s2[2][4];
#pragma unroll
  for (int i2 = 0; i2 < 2; ++i2)
#pragma unroll
    for (int j = 0; j < 4; ++j) s2[i2][j] = (f32x4){0.f, 0.f, 0.f, 0.f};
#pragma unroll
  for (int kk = 0; kk < 64; kk += 32) {
    f16x8 aq0 = *(const f16x8*)&sQh[(wn * 32 + r) * 72 + kk + q * 8];
    f16x8 aq1 = *(const f16x8*)&sQh[(wn * 32 + 16 + r) * 72 + kk + q * 8];
#pragma unroll
    for (int j = 0; j < 4; ++j) {
      f16x8 bk8 = *(const f16x8*)&sKh[(j * 16 + r) * 72 + kk + q * 8];
      s2[0][j] = __builtin_amdgcn_mfma_f32_16x16x32_f16(aq0, bk8, s2[0][j], 0, 0, 0);
      s2[1][j] = __builtin_amdgcn_mfma_f32_16x16x32_f16(aq1, bk8, s2[1][j], 0, 0, 0);
    }
  }
  // softmax over w' (no scale in reference); lane holds S[row][col=j*16+r]
  float inv2[2][4];
#pragma unroll
  for (int i2 = 0; i2 < 2; ++i2)
#pragma unroll
    for (int reg = 0; reg < 4; ++reg) {
      float mx = fmaxf(fmaxf(s2[i2][0][reg], s2[i2][1][reg]),
                       fmaxf(s2[i2][2][reg], s2[i2][3][reg]));
#pragma unroll
      for (int o = 1; o < 16; o <<= 1) mx = fmaxf(mx, __shfl_xor(mx, o, 64));
      float p0 = __expf(s2[i2][0][reg] - mx);
      float p1 = __expf(s2[i2][1][reg] - mx);
      float p2 = __expf(s2[i2][2][reg] - mx);
      float p3 = __expf(s2[i2][3][reg] - mx);
      float sum = p0 + p1 + p2 + p3;
#pragma unroll
      for (int o = 1; o < 16; o <<= 1) sum += __shfl_xor(sum, o, 64);
      inv2[i2][reg] = 1.0f / sum;
      const int row = wn * 32 + i2 * 16 + q * 4 + reg;
      sPh[row * 72 + r] = f2h(p0);
      sPh[row * 72 + 16 + r] = f2h(p1);
      sPh[row * 72 + 32 + r] = f2h(p2);
      sPh[row * 72 + 48 + r] = f2h(p3);
    }
  __syncthreads();  // QK reads done before sO overlays sQ/sK; sP visible
  f32x4 o4[2][4];
#pragma unroll
  for (int i2 = 0; i2 < 2; ++i2)
#pragma unroll
    for (int jd = 0; jd < 4; ++jd) o4[i2][jd] = (f32x4){0.f, 0.f, 0.f, 0.f};
#pragma unroll
  for (int kk = 0; kk < 64; kk += 32) {
    f16x8 ap0 = *(const f16x8*)&sPh[(wn * 32 + r) * 72 + kk + q * 8];
    f16x8 ap1 = *(const f16x8*)&sPh[(wn * 32 + 16 + r) * 72 + kk + q * 8];
#pragma unroll
    for (int jd = 0; jd < 4; ++jd) {
      f16x8 bv8 = *(const f16x8*)&sVh[(jd * 16 + r) * 72 + kk + q * 8];
      o4[0][jd] = __builtin_amdgcn_mfma_f32_16x16x32_f16(ap0, bv8, o4[0][jd], 0, 0, 0);
      o4[1][jd] = __builtin_amdgcn_mfma_f32_16x16x32_f16(ap1, bv8, o4[1][jd], 0, 0, 0);
    }
  }
  float* sOh = (float*)(smem + wm * 27648);  // [64 d][66 w], overlays sQ[hs]+sK[hs]
#pragma unroll
  for (int i2 = 0; i2 < 2; ++i2)
#pragma unroll
    for (int jd = 0; jd < 4; ++jd) {
      const int d = jd * 16 + r;
#pragma unroll
      for (int reg = 0; reg < 4; ++reg) {
        const int w = wn * 32 + i2 * 16 + q * 4 + reg;
        sOh[d * 66 + w] = o4[i2][jd][reg] * inv2[i2][reg];
      }
    }
  __syncthreads();
  // out[b][head*64+d][h][w] = O[w][d] + x; coalesced float4 along w, both h-rows
  const int d = t >> 2, w0 = (t & 3) * 16;
#pragma unroll
  for (int hs = 0; hs < 2; ++hs) {
    const float* sO2 = (const float*)(smem + hs * 27648);
    const int h = ht * 2 + hs;
    const size_t obase = (((size_t)b * C_ + head * 64 + d) * H_ + h) * (size_t)W_ + w0;
    const float4* xr = (const float4*)(x + obase);
    float4* op = (float4*)(out + obase);
#pragma unroll
    for (int u = 0; u < 4; ++u) {
      float4 xv = xr[u];
      float4 ov;
      ov.x = sO2[d * 66 + w0 + u * 4 + 0] + xv.x;
      ov.y = sO2[d * 66 + w0 + u * 4 + 1] + xv.y;
      ov.z = sO2[d * 66 + w0 + u * 4 + 2] + xv.z;
      ov.w = sO2[d * 66 + w0 + u * 4 + 3] + xv.w;
      op[u] = ov;
    }
  }
}

extern "C" void kernel_launch(void* const* d_in, const int* in_sizes, int n_in,
                              void* d_out, int out_size, void* d_ws, size_t ws_size,
                              hipStream_t stream) {
  const float* x  = (const float*)d_in[0];
  const float* wq = (const float*)d_in[1];
  const float* bq = (const float*)d_in[2];
  const float* wk = (const float*)d_in[3];
  const float* bk = (const float*)d_in[4];
  const float* wv = (const float*)d_in[5];
  const float* bv = (const float*)d_in[6];
  float* out = (float*)d_out;
  char* ws = (char*)d_ws;
  // ws layout: Wc 1.5 MiB only (xT and QKV intermediates eliminated)
  unsigned short* Wc = (unsigned short*)ws;
  hipLaunchKernelGGL(rcca_cvtw,  dim3(768),  dim3(256), 0, stream, wq, wk, wv, Wc);
  hipLaunchKernelGGL(rcca_fused, dim3(4096), dim3(256), 0, stream, x, Wc, bq, bk, bv, out);
}